// Round 5
// baseline (141.418 us; speedup 1.0000x reference)
//
#include <hip/hip_runtime.h>
#include <math.h>

#define NP 8192
#define NF 16384
#define GQ 16
#define SPLIT 4
#define NFS (NF / SPLIT)   // faces per split = 4096
#define NG (NP / GQ)       // point groups = 512

// ---------------------------------------------------------------------------
// K0: face centers in f64 + |c|^2 (np: c=(v0+v1+v2)/3), plus Adagrad clr table
// ---------------------------------------------------------------------------
__global__ __launch_bounds__(256) void k_centers(const float* __restrict__ mV,
                                                 const int* __restrict__ mF,
                                                 double* __restrict__ ctr,
                                                 double* __restrict__ clrtab) {
    if (blockIdx.x == 0 && threadIdx.x < 50) {
        clrtab[threadIdx.x] = 0.2 / (1.0 + (double)threadIdx.x * 0.1);
    }
    int f = blockIdx.x * 256 + threadIdx.x;
    if (f >= NF) return;
    int i0 = mF[3*f+0], i1 = mF[3*f+1], i2 = mF[3*f+2];
    double cx = ((double)mV[3*i0+0] + (double)mV[3*i1+0] + (double)mV[3*i2+0]) / 3.0;
    double cy = ((double)mV[3*i0+1] + (double)mV[3*i1+1] + (double)mV[3*i2+1]) / 3.0;
    double cz = ((double)mV[3*i0+2] + (double)mV[3*i1+2] + (double)mV[3*i2+2]) / 3.0;
    ctr[4*f+0] = cx; ctr[4*f+1] = cy; ctr[4*f+2] = cz;
    ctr[4*f+3] = cx*cx + cy*cy + cz*cz;
}

// ---------------------------------------------------------------------------
// K1a: partial 1-NN. Block = (point-group g, face-split s). Scans faces
// [s*NFS, (s+1)*NFS), key = |c|^2 - 2 q.c (bit-identical formula to round 4).
// Lex (key, idx) reduction is order-independent -> outputs provably identical.
// 2048 blocks = full-chip wave residency (the round-4 bottleneck).
// ---------------------------------------------------------------------------
__global__ __launch_bounds__(256) void k_knn_part(const float* __restrict__ qV,
                                                  const double* __restrict__ ctr,
                                                  double* __restrict__ pkey,
                                                  int* __restrict__ pidx) {
    int g = blockIdx.x / SPLIT;
    int s = blockIdx.x % SPLIT;
    int pbase = g * GQ;
    int fbase = s * NFS;

    double qx[GQ], qy[GQ], qz[GQ];
    #pragma unroll
    for (int gg = 0; gg < GQ; ++gg) {
        int p = pbase + gg;
        qx[gg] = (double)qV[3*p+0];
        qy[gg] = (double)qV[3*p+1];
        qz[gg] = (double)qV[3*p+2];
    }
    double best[GQ]; int bidx[GQ];
    #pragma unroll
    for (int gg = 0; gg < GQ; ++gg) { best[gg] = 1e300; bidx[gg] = 0x7fffffff; }

    const double4* ctr4 = (const double4*)ctr;
    #pragma unroll 2
    for (int fo = threadIdx.x; fo < NFS; fo += 256) {
        int f = fbase + fo;
        double4 c = ctr4[f];
        #pragma unroll
        for (int gg = 0; gg < GQ; ++gg) {
            double dot = qx[gg]*c.x + qy[gg]*c.y + qz[gg]*c.z;
            double key = c.w - 2.0*dot;
            if (key < best[gg]) { best[gg] = key; bidx[gg] = f; }
        }
    }
    // wave (64-lane) reduction, lexicographic (key, idx)
    #pragma unroll
    for (int off = 32; off > 0; off >>= 1) {
        #pragma unroll
        for (int gg = 0; gg < GQ; ++gg) {
            double ov = __shfl_down(best[gg], off);
            int    oi = __shfl_down(bidx[gg], off);
            if (ov < best[gg] || (ov == best[gg] && oi < bidx[gg])) { best[gg] = ov; bidx[gg] = oi; }
        }
    }
    __shared__ double sv[4][GQ];
    __shared__ int    si[4][GQ];
    int wid = threadIdx.x >> 6, lane = threadIdx.x & 63;
    if (lane == 0) {
        #pragma unroll
        for (int gg = 0; gg < GQ; ++gg) { sv[wid][gg] = best[gg]; si[wid][gg] = bidx[gg]; }
    }
    __syncthreads();
    if (threadIdx.x == 0) {
        for (int gg = 0; gg < GQ; ++gg) {
            double bv = sv[0][gg]; int bi = si[0][gg];
            for (int w2 = 1; w2 < 4; ++w2) {
                double ov = sv[w2][gg]; int oi = si[w2][gg];
                if (ov < bv || (ov == bv && oi < bi)) { bv = ov; bi = oi; }
            }
            int slot = (g * SPLIT + s) * GQ + gg;
            pkey[slot] = bv;
            pidx[slot] = bi;
        }
    }
}

// ---------------------------------------------------------------------------
// K1b: reduce the SPLIT partials per point, exact np d2 for the winner,
// outlier test, final fidx/mask outputs.
// ---------------------------------------------------------------------------
__global__ __launch_bounds__(256) void k_knn_reduce(const float* __restrict__ qV,
                                                    const double* __restrict__ ctr,
                                                    const double* __restrict__ pkey,
                                                    const int* __restrict__ pidx,
                                                    float* __restrict__ out,
                                                    int* __restrict__ fidx_ws,
                                                    int* __restrict__ valid_ws) {
    int p = blockIdx.x * 256 + threadIdx.x;
    if (p >= NP) return;
    int g = p / GQ, j = p % GQ;
    double bv = 1e300; int bi = 0x7fffffff;
    #pragma unroll
    for (int s = 0; s < SPLIT; ++s) {
        int slot = (g * SPLIT + s) * GQ + j;
        double ov = pkey[slot]; int oi = pidx[slot];
        if (ov < bv || (ov == bv && oi < bi)) { bv = ov; bi = oi; }
    }
    // exact np d2 for the winning face (identical formula to round 4)
    const double4* ctr4 = (const double4*)ctr;
    double4 c = ctr4[bi];
    double qx = (double)qV[3*p+0], qy = (double)qV[3*p+1], qz = (double)qV[3*p+2];
    double dot = qx*c.x + qy*c.y + qz*c.z;
    double qq  = qx*qx + qy*qy + qz*qz;
    double d2  = (qq - 2.0*dot) + c.w;
    int outlier = (d2 > 0.1) ? 1 : 0;
    fidx_ws[p]  = bi;
    valid_ws[p] = 1 - outlier;
    out[p]        = (float)bi;               // output 0: spt_fidx
    out[3*NP + p] = outlier ? 1.0f : 0.0f;   // output 2: outlier_mask
}

// ---------------------------------------------------------------------------
// K2: denom = max(#valid, 1)
// ---------------------------------------------------------------------------
__global__ __launch_bounds__(256) void k_denom(const int* __restrict__ valid_ws,
                                               double* __restrict__ denom) {
    __shared__ int s[256];
    int acc = 0;
    for (int i = threadIdx.x; i < NP; i += 256) acc += valid_ws[i];
    s[threadIdx.x] = acc;
    __syncthreads();
    for (int off = 128; off > 0; off >>= 1) {
        if (threadIdx.x < off) s[threadIdx.x] += s[threadIdx.x + off];
        __syncthreads();
    }
    if (threadIdx.x == 0) {
        double d = (double)s[0];
        denom[0] = d > 1.0 ? d : 1.0;
    }
}

// ---------------------------------------------------------------------------
// K3: per-point 2x50-step Adagrad — BIT-IDENTICAL to the round-4 passing
// version (slim vw margin; do not perturb).
// ---------------------------------------------------------------------------
__global__ __launch_bounds__(256) void k_opt(const float* __restrict__ qV,
                                             const float* __restrict__ qN,
                                             const float* __restrict__ mV,
                                             const int* __restrict__ mF,
                                             const float* __restrict__ mN,
                                             const int* __restrict__ fidx_ws,
                                             const int* __restrict__ valid_ws,
                                             const double* __restrict__ denomp,
                                             const double* __restrict__ clrtab,
                                             float* __restrict__ out) {
    int p = blockIdx.x * 256 + threadIdx.x;
    if (p >= NP) return;
    const float third = (float)(1.0/3.0);
    if (!valid_ws[p]) {            // outlier: keeps init barycentric coords
        out[NP + 2*p + 0] = third;
        out[NP + 2*p + 1] = third;
        return;
    }
    double inv_denom = 1.0 / denomp[0];
    int f = fidx_ws[p];
    int i0 = mF[3*f+0], i1 = mF[3*f+1], i2 = mF[3*f+2];

    double V0x = mV[3*i0+0], V0y = mV[3*i0+1], V0z = mV[3*i0+2];
    double V1x = mV[3*i1+0], V1y = mV[3*i1+1], V1z = mV[3*i1+2];
    double V2x = mV[3*i2+0], V2y = mV[3*i2+1], V2z = mV[3*i2+2];
    double N0x = mN[3*i0+0], N0y = mN[3*i0+1], N0z = mN[3*i0+2];
    double N1x = mN[3*i1+0], N1y = mN[3*i1+1], N1z = mN[3*i1+2];
    double N2x = mN[3*i2+0], N2y = mN[3*i2+1], N2z = mN[3*i2+2];
    double qx  = qV[3*p+0],  qy  = qV[3*p+1],  qz  = qV[3*p+2];
    double qnx = qN[3*p+0],  qny = qN[3*p+1],  qnz = qN[3*p+2];

    double Eux = V0x - V2x, Euy = V0y - V2y, Euz = V0z - V2z;  // dcV/du
    double Ewx = V1x - V2x, Ewy = V1y - V2y, Ewz = V1z - V2z;  // dcV/dw
    double Fux = N0x - N2x, Fuy = N0y - N2y, Fuz = N0z - N2z;  // dn_raw/du
    double Fwx = N1x - N2x, Fwy = N1y - N2y, Fwz = N1z - N2z;  // dn_raw/dw
    double Kx  = V2x - qx,  Ky  = V2y - qy,  Kz  = V2z - qz;   // cv - q at uu=ww=0

    double u = 1.0/3.0, w = 1.0/3.0;
    double alpha = 1.0;
    for (int outer = 0; outer < 2; ++outer) {
        double du = 0.0, dw = 0.0, su = 0.0, sw = 0.0;
        for (int it = 0; it < 50; ++it) {
            double uu = u + du, ww = w + dw;
            // position term: rv = cv - q = uu*Eu + ww*Ew + K
            double rvx = uu*Eux + ww*Ewx + Kx;
            double rvy = uu*Euy + ww*Ewy + Ky;
            double rvz = uu*Euz + ww*Ewz + Kz;
            double L2v = rvx*rvx + rvy*rvy + rvz*rvz;
            double invLv = rsqrt(L2v);
            double gu = (rvx*Eux + rvy*Euy + rvz*Euz) * invLv;
            double gw = (rvx*Ewx + rvy*Ewy + rvz*Ewz) * invLv;
            // normal term: n = uu*Fu + ww*Fw + N2
            double nx = uu*Fux + ww*Fwx + N2x;
            double ny = uu*Fuy + ww*Fwy + N2y;
            double nz = uu*Fuz + ww*Fwz + N2z;
            double m2 = nx*nx + ny*ny + nz*nz;
            bool   mok = (m2 > 1e-24);           // <=> m > 1e-12
            double inv = mok ? rsqrt(m2) : 1e12; // 1/max(m,1e-12)
            double hx = nx*inv, hy = ny*inv, hz = nz*inv;
            double rnx = hx - qnx, rny = hy - qny, rnz = hz - qnz;
            double L2n = rnx*rnx + rny*rny + rnz*rnz;
            double invLn = rsqrt(L2n);
            double A_u = rnx*Fux + rny*Fuy + rnz*Fuz;
            double A_w = rnx*Fwx + rny*Fwy + rnz*Fwz;
            double B   = rnx*nx + rny*ny + rnz*nz;
            double C_u = nx*Fux + ny*Fuy + nz*Fuz;
            double C_w = nx*Fwx + ny*Fwy + nz*Fwz;
            // s = B/m^3 when m > eps else 0 (original dropped the term there)
            double s = mok ? ((B*inv)*inv)*inv : 0.0;
            double gnu = (A_u*inv - s*C_u) * invLn;
            double gnw = (A_w*inv - s*C_w) * invLn;
            gu = (gu + 0.01*gnu) * inv_denom;   // mask=1, masked-mean scaling
            gw = (gw + 0.01*gnw) * inv_denom;
            // Adagrad(lr=0.2, lr_decay=0.1)
            su += gu*gu; sw += gw*gw;
            double clr = clrtab[it];
            du -= clr * gu / (sqrt(su) + 1e-10);
            dw -= clr * gw / (sqrt(sw) + 1e-10);
        }
        u += du * alpha; w += dw * alpha;
        alpha *= 0.5;
    }
    out[NP + 2*p + 0] = (float)u;
    out[NP + 2*p + 1] = (float)w;
}

// ---------------------------------------------------------------------------
extern "C" void kernel_launch(void* const* d_in, const int* in_sizes, int n_in,
                              void* d_out, int out_size, void* d_ws, size_t ws_size,
                              hipStream_t stream) {
    const float* qV = (const float*)d_in[0];   // query_V [1,8192,3]
    const float* qN = (const float*)d_in[1];   // query_N [1,8192,3]
    const float* mV = (const float*)d_in[2];   // mesh_V  [16384,3]
    const int*   mF = (const int*)d_in[3];     // mesh_F  [16384,3] int32
    const float* mN = (const float*)d_in[4];   // mesh_N  [16384,3]
    float* out = (float*)d_out;                // fidx | vw | outlier_mask

    double* ctr      = (double*)d_ws;             // NF*4 doubles (512 KB)
    double* denom    = ctr + (size_t)NF*4;        // 1 double
    double* clrtab   = denom + 1;                 // 50 doubles
    double* pkey     = clrtab + 50;               // NG*SPLIT*GQ doubles (256 KB)
    int*    pidx     = (int*)(pkey + (size_t)NG*SPLIT*GQ);  // NG*SPLIT*GQ ints
    int*    fidx_ws  = pidx + (size_t)NG*SPLIT*GQ;          // NP ints
    int*    valid_ws = fidx_ws + NP;                        // NP ints

    hipLaunchKernelGGL(k_centers,    dim3(NF/256),   dim3(256), 0, stream, mV, mF, ctr, clrtab);
    hipLaunchKernelGGL(k_knn_part,   dim3(NG*SPLIT), dim3(256), 0, stream, qV, ctr, pkey, pidx);
    hipLaunchKernelGGL(k_knn_reduce, dim3(NP/256),   dim3(256), 0, stream, qV, ctr, pkey, pidx,
                       out, fidx_ws, valid_ws);
    hipLaunchKernelGGL(k_denom,      dim3(1),        dim3(256), 0, stream, valid_ws, denom);
    hipLaunchKernelGGL(k_opt,        dim3(NP/256),   dim3(256), 0, stream,
                       qV, qN, mV, mF, mN, fidx_ws, valid_ws, denom, clrtab, out);
}

// Round 6
// 121.813 us; speedup vs baseline: 1.1609x; 1.1609x over previous
//
#include <hip/hip_runtime.h>
#include <math.h>

#define NP 8192
#define NF 16384
#define GQ 8
#define MARGIN 1e-5f   // f32 key abs-error bound ~1.5e-6; 6x safety

// ---------------------------------------------------------------------------
// K0: face centers: f64 (cx,cy,cz,|c|^2) for exact d2/repair, f32 copy for
// the fast scan, plus Adagrad clr table. np: c=(v0+v1+v2)/3 in f64.
// ---------------------------------------------------------------------------
__global__ __launch_bounds__(256) void k_centers(const float* __restrict__ mV,
                                                 const int* __restrict__ mF,
                                                 double* __restrict__ ctr,
                                                 float4* __restrict__ ctrf,
                                                 double* __restrict__ clrtab) {
    if (blockIdx.x == 0 && threadIdx.x < 50) {
        clrtab[threadIdx.x] = 0.2 / (1.0 + (double)threadIdx.x * 0.1);
    }
    int f = blockIdx.x * 256 + threadIdx.x;
    if (f >= NF) return;
    int i0 = mF[3*f+0], i1 = mF[3*f+1], i2 = mF[3*f+2];
    double cx = ((double)mV[3*i0+0] + (double)mV[3*i1+0] + (double)mV[3*i2+0]) / 3.0;
    double cy = ((double)mV[3*i0+1] + (double)mV[3*i1+1] + (double)mV[3*i2+1]) / 3.0;
    double cz = ((double)mV[3*i0+2] + (double)mV[3*i1+2] + (double)mV[3*i2+2]) / 3.0;
    double cc = cx*cx + cy*cy + cz*cz;
    ctr[4*f+0] = cx; ctr[4*f+1] = cy; ctr[4*f+2] = cz; ctr[4*f+3] = cc;
    ctrf[f] = make_float4((float)cx, (float)cy, (float)cz, (float)cc);
}

// ---------------------------------------------------------------------------
// K1: f32 1-NN scan with top-2 tracking. GQ=8, 1024 blocks (the empirically
// best shape). key = cc - 2 q.c. Per-point: winner (b1,i1) lex-min, runner-up
// value b2. gap = b2-b1 < MARGIN  => flagged for exact f64 repair.
// For gap >= MARGIN the f32 winner == f64-key winner (error bound).
// Thread0 finishes: exact f64 d2 for winner -> outlier test, writes outputs.
// ---------------------------------------------------------------------------
__global__ __launch_bounds__(256) void k_knn(const float* __restrict__ qV,
                                             const float4* __restrict__ ctrf,
                                             const double* __restrict__ ctr,
                                             float* __restrict__ out,
                                             int* __restrict__ fidx_ws,
                                             int* __restrict__ valid_ws,
                                             int* __restrict__ flag) {
    int pbase = blockIdx.x * GQ;
    float qx[GQ], qy[GQ], qz[GQ];
    #pragma unroll
    for (int g = 0; g < GQ; ++g) {
        int p = pbase + g;
        qx[g] = qV[3*p+0];
        qy[g] = qV[3*p+1];
        qz[g] = qV[3*p+2];
    }
    float b1[GQ], b2[GQ]; int i1[GQ];
    #pragma unroll
    for (int g = 0; g < GQ; ++g) { b1[g] = 1e30f; b2[g] = 1e30f; i1[g] = 0x7fffffff; }

    #pragma unroll 2
    for (int f = threadIdx.x; f < NF; f += 256) {
        float4 c = ctrf[f];
        #pragma unroll
        for (int g = 0; g < GQ; ++g) {
            float dot = qx[g]*c.x + qy[g]*c.y + qz[g]*c.z;
            float key = c.w - 2.0f*dot;
            float ob1 = b1[g];
            bool lt = key < ob1;
            b1[g] = lt ? key : ob1;               // v_min
            i1[g] = lt ? f : i1[g];               // cndmask
            float cand2 = lt ? ob1 : key;         // v_max(ob1,key)
            b2[g] = cand2 < b2[g] ? cand2 : b2[g];// v_min
        }
    }
    // wave (64-lane) top-2 merge, lex (b1,i1) for the winner
    #pragma unroll
    for (int off = 32; off > 0; off >>= 1) {
        #pragma unroll
        for (int g = 0; g < GQ; ++g) {
            float ob1 = __shfl_down(b1[g], off);
            int   oi1 = __shfl_down(i1[g], off);
            float ob2 = __shfl_down(b2[g], off);
            bool win = (ob1 < b1[g]) || (ob1 == b1[g] && oi1 < i1[g]);
            float loser = win ? b1[g] : ob1;
            b1[g] = win ? ob1 : b1[g];
            i1[g] = win ? oi1 : i1[g];
            float mb2 = ob2 < b2[g] ? ob2 : b2[g];
            b2[g] = loser < mb2 ? loser : mb2;
        }
    }
    __shared__ float sv1[4][GQ], sv2[4][GQ];
    __shared__ int   si1[4][GQ];
    int wid = threadIdx.x >> 6, lane = threadIdx.x & 63;
    if (lane == 0) {
        #pragma unroll
        for (int g = 0; g < GQ; ++g) { sv1[wid][g] = b1[g]; si1[wid][g] = i1[g]; sv2[wid][g] = b2[g]; }
    }
    __syncthreads();
    if (threadIdx.x == 0) {
        const double4* ctr4 = (const double4*)ctr;
        for (int g = 0; g < GQ; ++g) {
            float bv = sv1[0][g], r2 = sv2[0][g]; int bi = si1[0][g];
            for (int w2 = 1; w2 < 4; ++w2) {
                float ob1 = sv1[w2][g], ob2 = sv2[w2][g]; int oi1 = si1[w2][g];
                bool win = (ob1 < bv) || (ob1 == bv && oi1 < bi);
                float loser = win ? bv : ob1;
                bv = win ? ob1 : bv;
                bi = win ? oi1 : bi;
                float mb2 = ob2 < r2 ? ob2 : r2;
                r2 = loser < mb2 ? loser : mb2;
            }
            int p = pbase + g;
            flag[p] = (r2 - bv < MARGIN) ? 1 : 0;
            // exact np d2 for the winning face (f64)
            double4 c = ctr4[bi];
            double dqx = (double)qx[g], dqy = (double)qy[g], dqz = (double)qz[g];
            double dot = dqx*c.x + dqy*c.y + dqz*c.z;
            double qq  = dqx*dqx + dqy*dqy + dqz*dqz;
            double d2  = (qq - 2.0*dot) + c.w;
            int outlier = (d2 > 0.1) ? 1 : 0;
            fidx_ws[p]  = bi;
            valid_ws[p] = 1 - outlier;
            out[p]        = (float)bi;               // output 0: spt_fidx
            out[3*NP + p] = outlier ? 1.0f : 0.0f;   // output 2: outlier_mask
        }
    }
}

// ---------------------------------------------------------------------------
// K1b: exact f64 repair for flagged points (f32 gap < MARGIN). Full rescan
// with the round-4 f64 key, lex (key, idx) — identical semantics to the
// all-f64 rounds. One block per point; unflagged blocks exit immediately.
// ---------------------------------------------------------------------------
__global__ __launch_bounds__(256) void k_repair(const float* __restrict__ qV,
                                                const double* __restrict__ ctr,
                                                const int* __restrict__ flag,
                                                float* __restrict__ out,
                                                int* __restrict__ fidx_ws,
                                                int* __restrict__ valid_ws) {
    int p = blockIdx.x;
    if (!flag[p]) return;
    double qx = (double)qV[3*p+0], qy = (double)qV[3*p+1], qz = (double)qV[3*p+2];
    double best = 1e300; int bidx = 0x7fffffff;
    const double4* ctr4 = (const double4*)ctr;
    for (int f = threadIdx.x; f < NF; f += 256) {
        double4 c = ctr4[f];
        double dot = qx*c.x + qy*c.y + qz*c.z;
        double key = c.w - 2.0*dot;
        if (key < best) { best = key; bidx = f; }   // ascending f: strict < = lex
    }
    #pragma unroll
    for (int off = 32; off > 0; off >>= 1) {
        double ov = __shfl_down(best, off);
        int    oi = __shfl_down(bidx, off);
        if (ov < best || (ov == best && oi < bidx)) { best = ov; bidx = oi; }
    }
    __shared__ double sv[4];
    __shared__ int    si[4];
    int wid = threadIdx.x >> 6, lane = threadIdx.x & 63;
    if (lane == 0) { sv[wid] = best; si[wid] = bidx; }
    __syncthreads();
    if (threadIdx.x == 0) {
        double bv = sv[0]; int bi = si[0];
        for (int w2 = 1; w2 < 4; ++w2) {
            double ov = sv[w2]; int oi = si[w2];
            if (ov < bv || (ov == bv && oi < bi)) { bv = ov; bi = oi; }
        }
        double4 c = ctr4[bi];
        double dot = qx*c.x + qy*c.y + qz*c.z;
        double qq  = qx*qx + qy*qy + qz*qz;
        double d2  = (qq - 2.0*dot) + c.w;
        int outlier = (d2 > 0.1) ? 1 : 0;
        fidx_ws[p]  = bi;
        valid_ws[p] = 1 - outlier;
        out[p]        = (float)bi;
        out[3*NP + p] = outlier ? 1.0f : 0.0f;
    }
}

// ---------------------------------------------------------------------------
// K2: denom = max(#valid, 1)
// ---------------------------------------------------------------------------
__global__ __launch_bounds__(256) void k_denom(const int* __restrict__ valid_ws,
                                               double* __restrict__ denom) {
    __shared__ int s[256];
    int acc = 0;
    for (int i = threadIdx.x; i < NP; i += 256) acc += valid_ws[i];
    s[threadIdx.x] = acc;
    __syncthreads();
    for (int off = 128; off > 0; off >>= 1) {
        if (threadIdx.x < off) s[threadIdx.x] += s[threadIdx.x + off];
        __syncthreads();
    }
    if (threadIdx.x == 0) {
        double d = (double)s[0];
        denom[0] = d > 1.0 ? d : 1.0;
    }
}

// ---------------------------------------------------------------------------
// K3: per-point 2x50-step Adagrad — BIT-IDENTICAL to the round-4 passing
// version (slim vw margin; do not perturb).
// ---------------------------------------------------------------------------
__global__ __launch_bounds__(256) void k_opt(const float* __restrict__ qV,
                                             const float* __restrict__ qN,
                                             const float* __restrict__ mV,
                                             const int* __restrict__ mF,
                                             const float* __restrict__ mN,
                                             const int* __restrict__ fidx_ws,
                                             const int* __restrict__ valid_ws,
                                             const double* __restrict__ denomp,
                                             const double* __restrict__ clrtab,
                                             float* __restrict__ out) {
    int p = blockIdx.x * 256 + threadIdx.x;
    if (p >= NP) return;
    const float third = (float)(1.0/3.0);
    if (!valid_ws[p]) {            // outlier: keeps init barycentric coords
        out[NP + 2*p + 0] = third;
        out[NP + 2*p + 1] = third;
        return;
    }
    double inv_denom = 1.0 / denomp[0];
    int f = fidx_ws[p];
    int i0 = mF[3*f+0], i1 = mF[3*f+1], i2 = mF[3*f+2];

    double V0x = mV[3*i0+0], V0y = mV[3*i0+1], V0z = mV[3*i0+2];
    double V1x = mV[3*i1+0], V1y = mV[3*i1+1], V1z = mV[3*i1+2];
    double V2x = mV[3*i2+0], V2y = mV[3*i2+1], V2z = mV[3*i2+2];
    double N0x = mN[3*i0+0], N0y = mN[3*i0+1], N0z = mN[3*i0+2];
    double N1x = mN[3*i1+0], N1y = mN[3*i1+1], N1z = mN[3*i1+2];
    double N2x = mN[3*i2+0], N2y = mN[3*i2+1], N2z = mN[3*i2+2];
    double qx  = qV[3*p+0],  qy  = qV[3*p+1],  qz  = qV[3*p+2];
    double qnx = qN[3*p+0],  qny = qN[3*p+1],  qnz = qN[3*p+2];

    double Eux = V0x - V2x, Euy = V0y - V2y, Euz = V0z - V2z;  // dcV/du
    double Ewx = V1x - V2x, Ewy = V1y - V2y, Ewz = V1z - V2z;  // dcV/dw
    double Fux = N0x - N2x, Fuy = N0y - N2y, Fuz = N0z - N2z;  // dn_raw/du
    double Fwx = N1x - N2x, Fwy = N1y - N2y, Fwz = N1z - N2z;  // dn_raw/dw
    double Kx  = V2x - qx,  Ky  = V2y - qy,  Kz  = V2z - qz;   // cv - q at uu=ww=0

    double u = 1.0/3.0, w = 1.0/3.0;
    double alpha = 1.0;
    for (int outer = 0; outer < 2; ++outer) {
        double du = 0.0, dw = 0.0, su = 0.0, sw = 0.0;
        for (int it = 0; it < 50; ++it) {
            double uu = u + du, ww = w + dw;
            // position term: rv = cv - q = uu*Eu + ww*Ew + K
            double rvx = uu*Eux + ww*Ewx + Kx;
            double rvy = uu*Euy + ww*Ewy + Ky;
            double rvz = uu*Euz + ww*Ewz + Kz;
            double L2v = rvx*rvx + rvy*rvy + rvz*rvz;
            double invLv = rsqrt(L2v);
            double gu = (rvx*Eux + rvy*Euy + rvz*Euz) * invLv;
            double gw = (rvx*Ewx + rvy*Ewy + rvz*Ewz) * invLv;
            // normal term: n = uu*Fu + ww*Fw + N2
            double nx = uu*Fux + ww*Fwx + N2x;
            double ny = uu*Fuy + ww*Fwy + N2y;
            double nz = uu*Fuz + ww*Fwz + N2z;
            double m2 = nx*nx + ny*ny + nz*nz;
            bool   mok = (m2 > 1e-24);           // <=> m > 1e-12
            double inv = mok ? rsqrt(m2) : 1e12; // 1/max(m,1e-12)
            double hx = nx*inv, hy = ny*inv, hz = nz*inv;
            double rnx = hx - qnx, rny = hy - qny, rnz = hz - qnz;
            double L2n = rnx*rnx + rny*rny + rnz*rnz;
            double invLn = rsqrt(L2n);
            double A_u = rnx*Fux + rny*Fuy + rnz*Fuz;
            double A_w = rnx*Fwx + rny*Fwy + rnz*Fwz;
            double B   = rnx*nx + rny*ny + rnz*nz;
            double C_u = nx*Fux + ny*Fuy + nz*Fuz;
            double C_w = nx*Fwx + ny*Fwy + nz*Fwz;
            // s = B/m^3 when m > eps else 0 (original dropped the term there)
            double s = mok ? ((B*inv)*inv)*inv : 0.0;
            double gnu = (A_u*inv - s*C_u) * invLn;
            double gnw = (A_w*inv - s*C_w) * invLn;
            gu = (gu + 0.01*gnu) * inv_denom;   // mask=1, masked-mean scaling
            gw = (gw + 0.01*gnw) * inv_denom;
            // Adagrad(lr=0.2, lr_decay=0.1)
            su += gu*gu; sw += gw*gw;
            double clr = clrtab[it];
            du -= clr * gu / (sqrt(su) + 1e-10);
            dw -= clr * gw / (sqrt(sw) + 1e-10);
        }
        u += du * alpha; w += dw * alpha;
        alpha *= 0.5;
    }
    out[NP + 2*p + 0] = (float)u;
    out[NP + 2*p + 1] = (float)w;
}

// ---------------------------------------------------------------------------
extern "C" void kernel_launch(void* const* d_in, const int* in_sizes, int n_in,
                              void* d_out, int out_size, void* d_ws, size_t ws_size,
                              hipStream_t stream) {
    const float* qV = (const float*)d_in[0];   // query_V [1,8192,3]
    const float* qN = (const float*)d_in[1];   // query_N [1,8192,3]
    const float* mV = (const float*)d_in[2];   // mesh_V  [16384,3]
    const int*   mF = (const int*)d_in[3];     // mesh_F  [16384,3] int32
    const float* mN = (const float*)d_in[4];   // mesh_N  [16384,3]
    float* out = (float*)d_out;                // fidx | vw | outlier_mask

    double* ctr      = (double*)d_ws;             // NF*4 doubles (512 KB)
    double* denom    = ctr + (size_t)NF*4;        // 1 double
    double* clrtab   = denom + 1;                 // 50 doubles
    float4* ctrf     = (float4*)(clrtab + 50);    // NF float4 (256 KB)
    int*    flag     = (int*)(ctrf + NF);         // NP ints
    int*    fidx_ws  = flag + NP;                 // NP ints
    int*    valid_ws = fidx_ws + NP;              // NP ints

    hipLaunchKernelGGL(k_centers, dim3(NF/256), dim3(256), 0, stream, mV, mF, ctr, ctrf, clrtab);
    hipLaunchKernelGGL(k_knn,     dim3(NP/GQ),  dim3(256), 0, stream, qV, ctrf, ctr,
                       out, fidx_ws, valid_ws, flag);
    hipLaunchKernelGGL(k_repair,  dim3(NP),     dim3(256), 0, stream, qV, ctr, flag,
                       out, fidx_ws, valid_ws);
    hipLaunchKernelGGL(k_denom,   dim3(1),      dim3(256), 0, stream, valid_ws, denom);
    hipLaunchKernelGGL(k_opt,     dim3(NP/256), dim3(256), 0, stream,
                       qV, qN, mV, mF, mN, fidx_ws, valid_ws, denom, clrtab, out);
}